// Round 1
// baseline (446.803 us; speedup 1.0000x reference)
//
#include <hip/hip_runtime.h>

#define TLEN 4096
#define NROWS 16384      // B*C = 16*1024
#define VEC_PER_ROW 1024 // TLEN/4
#define SEGS 4           // 1024 vecs / 256 threads

__global__ __launch_bounds__(256) void lconv7_kernel(const float* __restrict__ x,
                                                     const float* __restrict__ wraw,
                                                     float* __restrict__ out) {
    const int bid = blockIdx.x;
    const int row = bid >> 2;        // [0, 16384)
    const int seg = bid & 3;
    const int tid = threadIdx.x;
    const int h   = row & 15;        // head = c % 16

    // --- softmax over the 7 taps (redundant per-thread; same addr per block -> cache broadcast) ---
    float w[7];
    float m = -1e30f;
#pragma unroll
    for (int k = 0; k < 7; ++k) {
        w[k] = wraw[h * 7 + k];
        m = fmaxf(m, w[k]);
    }
    float s = 0.0f;
#pragma unroll
    for (int k = 0; k < 7; ++k) {
        w[k] = __expf(w[k] - m);
        s += w[k];
    }
    const float inv = __frcp_rn(s);
#pragma unroll
    for (int k = 0; k < 7; ++k) w[k] *= inv;

    // --- load 12 contiguous elements (t0-4 .. t0+7) as three float4 ---
    const size_t base = (size_t)row * TLEN;
    const float4* rowv = (const float4*)(x + base);
    const int v = seg * 256 + tid;   // vector index in [0, 1024)

    const float4 Z = make_float4(0.f, 0.f, 0.f, 0.f);
    float4 L = (v > 0)    ? rowv[v - 1] : Z;   // t0-4..t0-1 (zeros at row start)
    float4 M = rowv[v];                        // t0..t0+3
    float4 R = (v < VEC_PER_ROW - 1) ? rowv[v + 1] : Z; // t0+4..t0+7 (zeros at row end)

    float xa[12] = {L.x, L.y, L.z, L.w, M.x, M.y, M.z, M.w, R.x, R.y, R.z, R.w};

    // out[t0+j] = sum_k w[k] * x[t0+j+k-3] = sum_k w[k] * xa[j+k+1]
    float4 o;
    float* op = &o.x;
#pragma unroll
    for (int j = 0; j < 4; ++j) {
        float acc = 0.0f;
#pragma unroll
        for (int k = 0; k < 7; ++k) acc = fmaf(w[k], xa[j + k + 1], acc);
        op[j] = acc;
    }

    ((float4*)(out + base))[v] = o;
}

extern "C" void kernel_launch(void* const* d_in, const int* in_sizes, int n_in,
                              void* d_out, int out_size, void* d_ws, size_t ws_size,
                              hipStream_t stream) {
    const float* x    = (const float*)d_in[0];   // (16,1024,4096) fp32
    const float* wgt  = (const float*)d_in[1];   // (16,1,7) fp32
    float*       outp = (float*)d_out;           // (16,1024,4096) fp32

    const int grid = NROWS * SEGS;               // 65536 blocks of 256 threads
    lconv7_kernel<<<grid, 256, 0, stream>>>(x, wgt, outp);
}